// Round 23
// baseline (229.005 us; speedup 1.0000x reference)
//
#include <hip/hip_runtime.h>
#include <math.h>

// LMHT neuron forward — SOLVED SEMANTICS (R18-R22: absmax = 0.0 bit-exact):
//   v   = (v + x[t]) + Iz                      fp32, left-assoc
//   q   = clip(floor(fl32(v/s)), 0, 4)         canonical quantizer (fp32-grid
//                                              compares derived via R5 proof)
//   o   = fl32(q*s);  spike = o - Iz
//   v   = fmaf(-q, s, v)                       single-rounded v - q*s (the npz
//                                              generator's XLA/LLVM fma fusion)
//
// R23 = burst-width experiment: 2x float4 per thread per plane (32 B/lane,
// 2 KB per wave-burst per stream) to halve the 8-stream switch rate and
// double load MLP. R22 = 196.9 us = 5.45 TB/s (87% of the 2-stream copy
// ceiling 6.29); traffic is provably minimal (FETCH=WRITE=525 MB ideal).
// If flat: the mixed-8-stream pattern IS the roofline; stop.

#pragma clang fp contract(off)

#define LMHT_T 4

typedef float f32x4v __attribute__((ext_vector_type(4)));

__device__ __forceinline__ float nextupf_pos(float a) {
    return __uint_as_float(__float_as_uint(a) + 1u);   // a > 0, finite
}

// smallest fp32 >= T (T > 0)
__device__ __forceinline__ float ceil_f32(double T) {
    float f = (float)T;                    // RNE
    if ((double)f < T) f = nextupf_pos(f);
    return f;
}

__device__ __forceinline__ float lmht_step(float& v, float xt, float s, float Iz,
                                           float c1, float c2, float c3, float c4) {
#pragma clang fp contract(off)
    v = (v + xt) + Iz;                       // fp32, left-assoc as in the source
    int q = (v >= c1) + (v >= c2) + (v >= c3) + (v >= c4); // canonical quantizer
    float o = (float)q * s;                  // spike level fl32(q*s)
    v = fmaf(-(float)q, s, v);               // carry: single-rounded v - q*s (ref fma)
    return o - Iz;
}

__global__ __launch_bounds__(256) void lmht_kernel(
    const float4* __restrict__ x,      // (T, ND/4) fp32
    const float* __restrict__ scale_p, // scalar fp32
    const float* __restrict__ zp_p,    // scalar fp32
    float4* __restrict__ out,          // (T, ND/4) fp32
    long long nd8)                     // elements-per-timestep / 8
{
#pragma clang fp contract(off)
    const float s   = fminf(fmaxf(scale_p[0], 1e-4f), 1e4f);       // fp32 params
    const float rzp = fminf(fmaxf(rintf(zp_p[0]), 0.0f), 15.0f);   // np.round half-even
    const float Iz  = (rzp * 0.25f) * s;     // fl(0.75*s)
    const float v0  = s * 0.5f;              // exact

    const double sd = (double)s;
    // R5 midpoints snapped UP to the fp32 grid (q-preserving for fp32 v).
    const float c1 = ceil_f32(sd * (1.0 - 0x1p-25));
    const float c2 = ceil_f32(sd * (2.0 - 0x1p-24));
    const float c3 = ceil_f32(sd * (3.0 - 0x1p-23));
    const float c4 = ceil_f32(sd * (4.0 - 0x1p-23));

    const long long nd4 = nd8 * 2;           // float4 count per plane

    long long idx    = (long long)blockIdx.x * blockDim.x + threadIdx.x;
    long long stride = (long long)gridDim.x * blockDim.x;

    for (long long i = idx; i < nd8; i += stride) {
        long long base = 2 * i;              // first of 2 consecutive float4s
        float va[8];
        #pragma unroll
        for (int e = 0; e < 8; ++e) va[e] = v0;
        #pragma unroll
        for (int t = 0; t < LMHT_T; ++t) {
            const f32x4v* xp = (const f32x4v*)&x[(long long)t * nd4 + base];
            f32x4v x0 = __builtin_nontemporal_load(xp);
            f32x4v x1 = __builtin_nontemporal_load(xp + 1);
            f32x4v o0, o1;
            o0.x = lmht_step(va[0], x0.x, s, Iz, c1, c2, c3, c4);
            o0.y = lmht_step(va[1], x0.y, s, Iz, c1, c2, c3, c4);
            o0.z = lmht_step(va[2], x0.z, s, Iz, c1, c2, c3, c4);
            o0.w = lmht_step(va[3], x0.w, s, Iz, c1, c2, c3, c4);
            o1.x = lmht_step(va[4], x1.x, s, Iz, c1, c2, c3, c4);
            o1.y = lmht_step(va[5], x1.y, s, Iz, c1, c2, c3, c4);
            o1.z = lmht_step(va[6], x1.z, s, Iz, c1, c2, c3, c4);
            o1.w = lmht_step(va[7], x1.w, s, Iz, c1, c2, c3, c4);
            f32x4v* op = (f32x4v*)&out[(long long)t * nd4 + base];
            __builtin_nontemporal_store(o0, op);
            __builtin_nontemporal_store(o1, op + 1);
        }
    }
}

extern "C" void kernel_launch(void* const* d_in, const int* in_sizes, int n_in,
                              void* d_out, int out_size, void* d_ws, size_t ws_size,
                              hipStream_t stream) {
    const float* x     = (const float*)d_in[0];
    const float* scale = (const float*)d_in[1];
    const float* zp    = (const float*)d_in[2];
    float* out         = (float*)d_out;

    long long total = (long long)in_sizes[0];      // T * N * D
    long long nd    = total / LMHT_T;              // per-timestep plane
    long long nd8   = nd / 8;                      // 2x float4 per thread

    const int block = 256;
    int grid = 4096;                               // grid-stride; ~4 iters/thread
    long long need = (nd8 + block - 1) / block;
    if (need < grid) grid = (int)need;

    lmht_kernel<<<grid, block, 0, stream>>>(
        (const float4*)x, scale, zp, (float4*)out, nd8);
}

// Round 24
// 198.070 us; speedup vs baseline: 1.1562x; 1.1562x over previous
//
#include <hip/hip_runtime.h>
#include <math.h>

// LMHT neuron forward — FINAL (revert to R22, the measured best: 196.9 us,
// 5.45 TB/s = 87% of the like-for-like copy ceiling; absmax = 0.0).
//
// SEMANTICS (pinned by R1-R18 forensics + oracle probes, bit-exact):
//   v   = (v + x[t]) + Iz                      fp32, left-assoc
//   q   = clip(floor(fl32(v/s)), 0, 4)         canonical quantizer, computed
//         division-free via fp32-grid thresholds c_m (snapped from the R5
//         midpoint doubles — exact for any correctly-rounded divide)
//   o   = fl32(q*s);  spike = o - Iz
//   v   = fmaf(-q, s, v)                       single-rounded v - q*s (the
//         npz generator's XLA/LLVM fma fusion — differs from v - fl32(q*s)
//         only at q=3; THE key semantic found in R18)
//
// PERF (R19->R22 ladder: 210.3 -> 203.3 -> 196.9 us):
//   * fp32-grid quantizer compares (no f64 chain)        [R21, -7 us]
//   * nontemporal loads AND stores (537 MB streamed each way, zero reuse,
//     >> 256 MB L3: cache allocation is pure overhead)   [R21/R22, -13 us]
//   * 16 B/lane, per-instruction coalesced, grid-stride  [R23's 32 B/lane
//     experiment REGRESSED to 229 us: lane-stride-32 halves per-instruction
//     coalescing density; do not widen]
// Traffic is provably minimal (FETCH=WRITE=525 MB ideal). Remaining gap to
// the 6.29 TB/s copy ceiling is the irreducible 8-stream (4R+4W) mix.

#pragma clang fp contract(off)

#define LMHT_T 4

typedef float f32x4v __attribute__((ext_vector_type(4)));

__device__ __forceinline__ float nextupf_pos(float a) {
    return __uint_as_float(__float_as_uint(a) + 1u);   // a > 0, finite
}

// smallest fp32 >= T (T > 0)
__device__ __forceinline__ float ceil_f32(double T) {
    float f = (float)T;                    // RNE
    if ((double)f < T) f = nextupf_pos(f);
    return f;
}

__device__ __forceinline__ float lmht_step(float& v, float xt, float s, float Iz,
                                           float c1, float c2, float c3, float c4) {
#pragma clang fp contract(off)
    v = (v + xt) + Iz;                       // fp32, left-assoc as in the source
    int q = (v >= c1) + (v >= c2) + (v >= c3) + (v >= c4); // canonical quantizer
    float o = (float)q * s;                  // spike level fl32(q*s)
    v = fmaf(-(float)q, s, v);               // carry: single-rounded v - q*s (ref fma)
    return o - Iz;
}

__global__ __launch_bounds__(256) void lmht_kernel(
    const float4* __restrict__ x,      // (T, ND/4) fp32
    const float* __restrict__ scale_p, // scalar fp32
    const float* __restrict__ zp_p,    // scalar fp32
    float4* __restrict__ out,          // (T, ND/4) fp32
    long long nd4)
{
#pragma clang fp contract(off)
    const float s   = fminf(fmaxf(scale_p[0], 1e-4f), 1e4f);       // fp32 params
    const float rzp = fminf(fmaxf(rintf(zp_p[0]), 0.0f), 15.0f);   // np.round half-even
    const float Iz  = (rzp * 0.25f) * s;     // fl(0.75*s)
    const float v0  = s * 0.5f;              // exact

    const double sd = (double)s;
    // R5 midpoints (exact for any correctly-rounded divide), snapped UP to
    // the fp32 grid: v >= c_m  <=>  (double)v >= sd*(m - h_m) for fp32 v.
    const float c1 = ceil_f32(sd * (1.0 - 0x1p-25));
    const float c2 = ceil_f32(sd * (2.0 - 0x1p-24));
    const float c3 = ceil_f32(sd * (3.0 - 0x1p-23));
    const float c4 = ceil_f32(sd * (4.0 - 0x1p-23));

    long long idx    = (long long)blockIdx.x * blockDim.x + threadIdx.x;
    long long stride = (long long)gridDim.x * blockDim.x;

    for (long long i = idx; i < nd4; i += stride) {
        float v0_ = v0, v1_ = v0, v2_ = v0, v3_ = v0;
        #pragma unroll
        for (int t = 0; t < LMHT_T; ++t) {
            f32x4v xt = __builtin_nontemporal_load(
                (const f32x4v*)&x[(long long)t * nd4 + i]);
            f32x4v ov;
            ov.x = lmht_step(v0_, xt.x, s, Iz, c1, c2, c3, c4);
            ov.y = lmht_step(v1_, xt.y, s, Iz, c1, c2, c3, c4);
            ov.z = lmht_step(v2_, xt.z, s, Iz, c1, c2, c3, c4);
            ov.w = lmht_step(v3_, xt.w, s, Iz, c1, c2, c3, c4);
            __builtin_nontemporal_store(ov, (f32x4v*)&out[(long long)t * nd4 + i]);
        }
    }
}

extern "C" void kernel_launch(void* const* d_in, const int* in_sizes, int n_in,
                              void* d_out, int out_size, void* d_ws, size_t ws_size,
                              hipStream_t stream) {
    const float* x     = (const float*)d_in[0];
    const float* scale = (const float*)d_in[1];
    const float* zp    = (const float*)d_in[2];
    float* out         = (float*)d_out;

    long long total = (long long)in_sizes[0];      // T * N * D
    long long nd    = total / LMHT_T;              // per-timestep plane
    long long nd4   = nd / 4;                      // float4 count

    const int block = 256;
    int grid = 4096;                               // grid-stride; ~8 iters/thread
    long long need = (nd4 + block - 1) / block;
    if (need < grid) grid = (int)need;

    lmht_kernel<<<grid, block, 0, stream>>>(
        (const float4*)x, scale, zp, (float4*)out, nd4);
}